// Round 2
// baseline (173.574 us; speedup 1.0000x reference)
//
#include <hip/hip_runtime.h>

#define NH  32
#define SEQ 2048
#define DIM 128
#define FD  32

typedef short          short8 __attribute__((ext_vector_type(8)));
typedef float          f32x4  __attribute__((ext_vector_type(4)));
typedef unsigned short u16x4  __attribute__((ext_vector_type(4)));

static __device__ __forceinline__ unsigned short f2bf(float f) {
    unsigned int u = __builtin_bit_cast(unsigned int, f);
    u += 0x7fffu + ((u >> 16) & 1u);            // round-to-nearest-even
    return (unsigned short)(u >> 16);
}
static __device__ __forceinline__ float fexp(float x) {          // e^x
    return __builtin_amdgcn_exp2f(x * 1.44269504088896f);
}
static __device__ __forceinline__ float sigm(float x) {
    return __builtin_amdgcn_rcpf(1.0f + fexp(-x));
}
static __device__ __forceinline__ float silu_f(float x) { return x * sigm(x); }
static __device__ __forceinline__ float tanh_f(float x) {
    return 1.0f - 2.0f * __builtin_amdgcn_rcpf(fexp(2.0f * x) + 1.0f);
}

// Stage a [rows][128] f32 matrix from global into LDS as bf16 with an XOR
// swizzle (ushort index: col ^ ((row&7)<<3)) so short8 fragment reads are
// bank-conflict-free. 128 threads.
static __device__ __forceinline__ void stage_mat(const float* __restrict__ src,
                                                 unsigned short* dst, int rows) {
    int t = threadIdx.x;
    int nit = rows >> 2;
    for (int it = 0; it < nit; ++it) {
        int row = it * 4 + (t >> 5);
        int c0  = (t & 31) * 4;
        f32x4 v = *(const f32x4*)(src + row * 128 + c0);
        u16x4 p;
        p[0] = f2bf(v[0]); p[1] = f2bf(v[1]); p[2] = f2bf(v[2]); p[3] = f2bf(v[3]);
        int base = row * 128 + (c0 ^ ((row & 7) << 3));
        *(u16x4*)(&dst[base]) = p;
    }
}

// One MLP layer for a 64-token tile, in place: load a-frags into registers,
// barrier, then compute out[t,o] = act(sum_k in[t,k]*W[o,k] + b[o]) and
// overwrite `act` (or write bf16 [tok][FD] to global for the last layer).
// 2 waves; each wave owns 32 token rows. OT = out_width/16. ACT: 0=silu,1=tanh.
template <int OT, int ACT, bool TOGLOB>
static __device__ __forceinline__ void mlp_layer(
    unsigned short* act, const unsigned short* w_lds,
    const float* __restrict__ bias, unsigned short* __restrict__ gout) {
    int lane = threadIdx.x & 63;
    int wid  = threadIdx.x >> 6;
    int kb   = (lane >> 4) * 8;

    short8 a[2][4];
#pragma unroll
    for (int rt = 0; rt < 2; ++rt) {
        int row = wid * 32 + rt * 16 + (lane & 15);
        int sw  = (row & 7) << 3;
#pragma unroll
        for (int ks = 0; ks < 4; ++ks)
            a[rt][ks] = *(const short8*)(&act[row * 128 + ((ks * 32 + kb) ^ sw)]);
    }
    __syncthreads();   // everyone's a-frags loaded before act is overwritten
#pragma unroll
    for (int ot = 0; ot < OT; ++ot) {
        int wrow = ot * 16 + (lane & 15);
        int sw   = (wrow & 7) << 3;
        short8 b[4];
#pragma unroll
        for (int ks = 0; ks < 4; ++ks)
            b[ks] = *(const short8*)(&w_lds[wrow * 128 + ((ks * 32 + kb) ^ sw)]);
        f32x4 acc0 = {0.f, 0.f, 0.f, 0.f};
        f32x4 acc1 = {0.f, 0.f, 0.f, 0.f};
#pragma unroll
        for (int ks = 0; ks < 4; ++ks) {
            acc0 = __builtin_amdgcn_mfma_f32_16x16x32_bf16(a[0][ks], b[ks], acc0, 0, 0, 0);
            acc1 = __builtin_amdgcn_mfma_f32_16x16x32_bf16(a[1][ks], b[ks], acc1, 0, 0, 0);
        }
        float bv = bias[ot * 16 + (lane & 15)];
#pragma unroll
        for (int rt = 0; rt < 2; ++rt) {
            f32x4 acc = rt ? acc1 : acc0;
#pragma unroll
            for (int r = 0; r < 4; ++r) {
                float y = acc[r] + bv;
                float v = (ACT == 0) ? silu_f(y) : tanh_f(y);
                int orow = wid * 32 + rt * 16 + (lane >> 4) * 4 + r;
                int ocol = ot * 16 + (lane & 15);
                if (TOGLOB)
                    gout[orow * FD + ocol] = f2bf(v);
                else
                    act[orow * 128 + (ocol ^ ((orow & 7) << 3))] = f2bf(v);
            }
        }
    }
}

__global__ __launch_bounds__(128) void mlp_kernel(
    const float* __restrict__ K,  const float* __restrict__ Q,
    const float* __restrict__ Wk1, const float* __restrict__ bk1,
    const float* __restrict__ Wk2, const float* __restrict__ bk2,
    const float* __restrict__ Wk3, const float* __restrict__ bk3,
    const float* __restrict__ Wq1, const float* __restrict__ bq1,
    const float* __restrict__ Wq2, const float* __restrict__ bq2,
    const float* __restrict__ Wq3, const float* __restrict__ bq3,
    unsigned short* __restrict__ Kl, unsigned short* __restrict__ Ql) {
    __shared__ unsigned short xb[64 * 128];    // 16 KB activations (in place)
    __shared__ unsigned short wb[128 * 128];   // 32 KB weights     -> 48 KB total
    int bid = blockIdx.x;
    int tb  = bid & 31;
    int h   = (bid >> 5) & 31;
    int src = bid >> 10;                        // 0 = K-net, 1 = Q-net

    const float* X  = src ? Q : K;
    const float* W1 = (src ? Wq1 : Wk1) + h * (128 * 128);
    const float* B1 = (src ? bq1 : bk1) + h * 128;
    const float* W2 = (src ? Wq2 : Wk2) + h * (128 * 128);
    const float* B2 = (src ? bq2 : bk2) + h * 128;
    const float* W3 = (src ? Wq3 : Wk3) + h * (FD * 128);
    const float* B3 = (src ? bq3 : bk3) + h * FD;
    unsigned short* gout = (src ? Ql : Kl) + ((size_t)h * SEQ + (size_t)tb * 64) * FD;
    const float* xs = X + ((size_t)h * SEQ + (size_t)tb * 64) * DIM;

    stage_mat(xs, xb, 64);
    stage_mat(W1, wb, 128);
    __syncthreads();
    mlp_layer<8, 0, false>(xb, wb, B1, nullptr);
    __syncthreads();
    stage_mat(W2, wb, 128);
    __syncthreads();
    mlp_layer<8, 0, false>(xb, wb, B2, nullptr);
    __syncthreads();
    stage_mat(W3, wb, 32);
    __syncthreads();
    mlp_layer<2, 1, true>(xb, wb, B3, gout);
}

// scores = Ql . Kl^T over F=32 (one MFMA K-step), causal mask,
// sigmoid(s - 0.5), FLOAT32 store. 128x128 tile per block; 64x64 per wave.
// Results bounce through a per-wave LDS half-tile (32 rows, stride 68 f32)
// so global stores are contiguous 32 B per lane.
__global__ __launch_bounds__(256) void score_kernel(
    const unsigned short* __restrict__ Ql, const unsigned short* __restrict__ Kl,
    float* __restrict__ out) {
    int bid = blockIdx.x;
    int h   = bid >> 8;
    int tr  = (bid >> 4) & 15;
    int tc  = bid & 15;
    int tq0 = tr * 128, tk0 = tc * 128;
    int tid = threadIdx.x;
    float* ob = out + (size_t)h * SEQ * SEQ;

    if (tc > tr) {                              // fully masked: sigmoid(-inf) = 0
        f32x4 z = {0.f, 0.f, 0.f, 0.f};
        for (int it = 0; it < 16; ++it) {
            int row = tq0 + it * 8 + (tid >> 5);
            int c0  = tk0 + (tid & 31) * 4;
            *(f32x4*)(ob + (size_t)row * SEQ + c0) = z;
        }
        return;
    }
    bool diag = (tc == tr);
    __shared__ float sb[4][32 * 68];            // 34 KB, per-wave private
    int lane = tid & 63;
    int wid  = tid >> 6;
    int tqw  = tq0 + (wid >> 1) * 64;
    int tkw  = tk0 + (wid & 1) * 64;
    int kb   = (lane >> 4) * 8;

    short8 aq[4], bk[4];
#pragma unroll
    for (int i = 0; i < 4; ++i) {
        aq[i] = *(const short8*)(Ql + ((size_t)h * SEQ + tqw + i * 16 + (lane & 15)) * FD + kb);
        bk[i] = *(const short8*)(Kl + ((size_t)h * SEQ + tkw + i * 16 + (lane & 15)) * FD + kb);
    }
    float* my = sb[wid];
#pragma unroll
    for (int half = 0; half < 2; ++half) {
#pragma unroll
        for (int rt2 = 0; rt2 < 2; ++rt2) {
            int rt = half * 2 + rt2;
#pragma unroll
            for (int ct = 0; ct < 4; ++ct) {
                f32x4 acc = {0.f, 0.f, 0.f, 0.f};
                acc = __builtin_amdgcn_mfma_f32_16x16x32_bf16(aq[rt], bk[ct], acc, 0, 0, 0);
#pragma unroll
                for (int r = 0; r < 4; ++r) {
                    int row = rt2 * 16 + (lane >> 4) * 4 + r;     // 0..31 in half
                    int col = ct * 16 + (lane & 15);
                    float o = sigm(acc[r] - 0.5f);
                    if (diag && (tkw + col) > (tqw + half * 32 + row)) o = 0.0f;
                    my[row * 68 + col] = o;
                }
            }
        }
        // write back 32 rows x 64 f32; each lane stores 32 contiguous bytes
#pragma unroll
        for (int it = 0; it < 4; ++it) {
            int row = it * 8 + (lane >> 3);
            int c0  = (lane & 7) * 8;
            f32x4 v0 = *(const f32x4*)(&my[row * 68 + c0]);
            f32x4 v1 = *(const f32x4*)(&my[row * 68 + c0 + 4]);
            float* dst = ob + (size_t)(tqw + half * 32 + row) * SEQ + tkw + c0;
            *(f32x4*)dst       = v0;
            *(f32x4*)(dst + 4) = v1;
        }
    }
}

extern "C" void kernel_launch(void* const* d_in, const int* in_sizes, int n_in,
                              void* d_out, int out_size, void* d_ws, size_t ws_size,
                              hipStream_t stream) {
    const float* K   = (const float*)d_in[0];
    const float* Q   = (const float*)d_in[1];
    const float* Wk1 = (const float*)d_in[2];
    const float* bk1 = (const float*)d_in[3];
    const float* Wk2 = (const float*)d_in[4];
    const float* bk2 = (const float*)d_in[5];
    const float* Wk3 = (const float*)d_in[6];
    const float* bk3 = (const float*)d_in[7];
    const float* Wq1 = (const float*)d_in[8];
    const float* bq1 = (const float*)d_in[9];
    const float* Wq2 = (const float*)d_in[10];
    const float* bq2 = (const float*)d_in[11];
    const float* Wq3 = (const float*)d_in[12];
    const float* bq3 = (const float*)d_in[13];

    unsigned short* Kl = (unsigned short*)d_ws;                   // [32][2048][32] bf16
    unsigned short* Ql = Kl + (size_t)NH * SEQ * FD;              // +4 MB

    mlp_kernel<<<dim3(2 * NH * (SEQ / 64)), dim3(128), 0, stream>>>(
        K, Q, Wk1, bk1, Wk2, bk2, Wk3, bk3, Wq1, bq1, Wq2, bq2, Wq3, bq3, Kl, Ql);

    score_kernel<<<dim3(NH * 16 * 16), dim3(256), 0, stream>>>(
        Ql, Kl, (float*)d_out);
}